// Round 1
// baseline (75.608 us; speedup 1.0000x reference)
//
#include <hip/hip_runtime.h>
#include <hip/hip_bf16.h>

#define B_   16
#define L_   256
#define D_   512
#define C_   8
#define P_   12
#define LOUT 244
#define O_   512

typedef __attribute__((ext_vector_type(8))) short bf16x8;
typedef __attribute__((ext_vector_type(4))) float f32x4;

__device__ __forceinline__ unsigned short f2bf(float f) {
    unsigned int u = __float_as_uint(f);
    unsigned int r = (u + 0x7FFFu + ((u >> 16) & 1u)) >> 16;
    return (unsigned short)r;
}

// ---------------------------------------------------------------------------
// K1: tmp[c][b][l][d] = sum_p Wt[c,p] * inp[b, l+p, d]   (bf16 out)
// grid: C_*B_*61 blocks, 256 threads; each thread: one d-pair, 4 l's.
// ---------------------------------------------------------------------------
__global__ __launch_bounds__(256) void tmp_build(const float* __restrict__ inp,
                                                 const float* __restrict__ Wt,
                                                 unsigned short* __restrict__ tmp) {
    int bid = blockIdx.x;              // 8*16*61 = 7808
    int lg = bid % 61; int t2 = bid / 61;
    int b = t2 % B_;  int c = t2 / B_;
    int l0 = lg * 4;
    int tid = threadIdx.x;
    int d0 = tid * 2;

    float wt[P_];
#pragma unroll
    for (int p = 0; p < P_; ++p) wt[p] = Wt[c * P_ + p];

    float2 rows[15];
    const float* ibase = inp + ((size_t)b * L_ + l0) * D_ + d0;
#pragma unroll
    for (int j = 0; j < 15; ++j)
        rows[j] = *(const float2*)(ibase + (size_t)j * D_);

    unsigned short* obase = tmp + ((size_t)(c * B_ + b) * LOUT + l0) * D_ + d0;
#pragma unroll
    for (int j = 0; j < 4; ++j) {
        float vx = 0.f, vy = 0.f;
#pragma unroll
        for (int p = 0; p < P_; ++p) {
            vx += wt[p] * rows[j + p].x;
            vy += wt[p] * rows[j + p].y;
        }
        ushort2 ov; ov.x = f2bf(vx); ov.y = f2bf(vy);
        *(ushort2*)(obase + (size_t)j * D_) = ov;
    }
}

// ---------------------------------------------------------------------------
// K1b: Ws f32 -> bf16  (2M elems, 4 per thread)
// ---------------------------------------------------------------------------
__global__ __launch_bounds__(256) void ws_convert(const float* __restrict__ Ws,
                                                  unsigned short* __restrict__ wsb) {
    int g = blockIdx.x * 256 + threadIdx.x;   // 524288 threads total
    float4 v = ((const float4*)Ws)[g];
    ushort4 o;
    o.x = f2bf(v.x); o.y = f2bf(v.y); o.z = f2bf(v.z); o.w = f2bf(v.w);
    ((ushort4*)wsb)[g] = o;
}

// ---------------------------------------------------------------------------
// K2: per (c,b): out[l,o] = tmp[l,:] . Ws[c,o,:] + S*bs[c,o] + bt[c]
// 64x64 tile, BK=64, 4 waves (2x2), 2x2 frags of v_mfma_f32_16x16x32_bf16
// ---------------------------------------------------------------------------
#define PADK 72   // bf16 stride: 144 B = 36 dwords -> conflict-free aggregate

__global__ __launch_bounds__(256) void gemm_k(const unsigned short* __restrict__ tmp,
                                              const unsigned short* __restrict__ wsb,
                                              const float* __restrict__ bs,
                                              const float* __restrict__ Wt,
                                              const float* __restrict__ bt,
                                              float* __restrict__ out) {
    __shared__ unsigned short As[64][PADK];
    __shared__ unsigned short Bs[64][PADK];

    int bid = blockIdx.x;              // 4096 = c(3b) | b(4b) | lt(2b) | ot(3b)
    int ot = bid & 7;
    int lt = (bid >> 3) & 3;
    int b  = (bid >> 5) & 15;
    int c  = bid >> 9;
    int l0 = lt * 64, o0 = ot * 64;

    int tid = threadIdx.x;
    int lane = tid & 63, wid = tid >> 6;
    int wm = wid >> 1, wn = wid & 1;

    const unsigned short* Ab = tmp + (size_t)(c * B_ + b) * LOUT * D_;
    const unsigned short* Bb = wsb + (size_t)c * O_ * D_;

    f32x4 acc[2][2];
#pragma unroll
    for (int m = 0; m < 2; ++m)
#pragma unroll
        for (int n = 0; n < 2; ++n)
            acc[m][n] = (f32x4){0.f, 0.f, 0.f, 0.f};

    for (int d0 = 0; d0 < D_; d0 += 64) {
        __syncthreads();
        // stage A and B tiles: 512 16B-chunks each; 2 per thread per tile
#pragma unroll
        for (int h = 0; h < 2; ++h) {
            int q = tid + h * 256;
            int row = q >> 3, ck = q & 7;
            int arow = l0 + row; if (arow > LOUT - 1) arow = LOUT - 1;
            uint4 va = *(const uint4*)(Ab + (size_t)arow * D_ + d0 + ck * 8);
            *(uint4*)&As[row][ck * 8] = va;
            uint4 vb = *(const uint4*)(Bb + (size_t)(o0 + row) * D_ + d0 + ck * 8);
            *(uint4*)&Bs[row][ck * 8] = vb;
        }
        __syncthreads();

#pragma unroll
        for (int kk = 0; kk < 2; ++kk) {
            int cb = kk * 32 + ((lane >> 4) << 3);
            bf16x8 af[2], bfr[2];
#pragma unroll
            for (int m = 0; m < 2; ++m)
                af[m] = *(const bf16x8*)&As[wm * 32 + m * 16 + (lane & 15)][cb];
#pragma unroll
            for (int n = 0; n < 2; ++n)
                bfr[n] = *(const bf16x8*)&Bs[wn * 32 + n * 16 + (lane & 15)][cb];
#pragma unroll
            for (int m = 0; m < 2; ++m)
#pragma unroll
                for (int n = 0; n < 2; ++n)
                    acc[m][n] = __builtin_amdgcn_mfma_f32_16x16x32_bf16(
                        af[m], bfr[n], acc[m][n], 0, 0, 0);
        }
    }

    float S = 0.f;
#pragma unroll
    for (int p = 0; p < P_; ++p) S += Wt[c * P_ + p];
    float btc = bt[c];

#pragma unroll
    for (int m = 0; m < 2; ++m) {
        int rbase = l0 + wm * 32 + m * 16 + ((lane >> 4) << 2);
#pragma unroll
        for (int n = 0; n < 2; ++n) {
            int col = o0 + wn * 32 + n * 16 + (lane & 15);
            float add = bs[c * O_ + col] * S + btc;
#pragma unroll
            for (int i = 0; i < 4; ++i) {
                int row = rbase + i;
                if (row < LOUT)
                    out[(((size_t)b * LOUT + row) * C_ + c) * O_ + col] =
                        acc[m][n][i] + add;
            }
        }
    }
}

// ---------------------------------------------------------------------------
// Fallback (ws too small): slow but correct, no workspace.
// ---------------------------------------------------------------------------
__global__ __launch_bounds__(256) void naive_k(const float* __restrict__ inp,
                                               const float* __restrict__ Ws,
                                               const float* __restrict__ bs,
                                               const float* __restrict__ Wt,
                                               const float* __restrict__ bt,
                                               float* __restrict__ out) {
    __shared__ float tmp[D_];
    int bid = blockIdx.x;              // B_*LOUT*C_
    int c = bid & 7; int r = bid >> 3;
    int l = r % LOUT; int b = r / LOUT;
    int tid = threadIdx.x;

    for (int d = tid; d < D_; d += 256) {
        float s = 0.f;
        for (int p = 0; p < P_; ++p)
            s += Wt[c * P_ + p] * inp[((size_t)b * L_ + l + p) * D_ + d];
        tmp[d] = s;
    }
    __syncthreads();
    float S = 0.f;
    for (int p = 0; p < P_; ++p) S += Wt[c * P_ + p];
    for (int o = tid; o < O_; o += 256) {
        const float* wrow = Ws + ((size_t)c * O_ + o) * D_;
        float s = 0.f;
        for (int d = 0; d < D_; ++d) s += wrow[d] * tmp[d];
        out[(((size_t)b * LOUT + l) * C_ + c) * O_ + o] =
            s + bs[c * O_ + o] * S + bt[c];
    }
}

extern "C" void kernel_launch(void* const* d_in, const int* in_sizes, int n_in,
                              void* d_out, int out_size, void* d_ws, size_t ws_size,
                              hipStream_t stream) {
    const float* inp = (const float*)d_in[0];
    const float* Ws  = (const float*)d_in[1];
    const float* bs  = (const float*)d_in[2];
    const float* Wt  = (const float*)d_in[3];
    const float* bt  = (const float*)d_in[4];
    float* out = (float*)d_out;

    const size_t TMPB = (size_t)C_ * B_ * LOUT * D_ * 2;   // 31,981,568
    const size_t WSBB = (size_t)C_ * O_ * D_ * 2;          //  4,194,304

    if (ws_size >= TMPB + WSBB) {
        unsigned short* tmpb = (unsigned short*)d_ws;
        unsigned short* wsb  = (unsigned short*)((char*)d_ws + TMPB);
        tmp_build<<<C_ * B_ * 61, 256, 0, stream>>>(inp, Wt, tmpb);
        ws_convert<<<2048, 256, 0, stream>>>(Ws, wsb);
        gemm_k<<<4096, 256, 0, stream>>>(tmpb, wsb, bs, Wt, bt, out);
    } else {
        naive_k<<<B_ * LOUT * C_, 256, 0, stream>>>(inp, Ws, bs, Wt, bt, out);
    }
}

// Round 2
// 50.269 us; speedup vs baseline: 1.5041x; 1.5041x over previous
//
#include <hip/hip_runtime.h>
#include <hip/hip_bf16.h>

#define B_   16
#define L_   256
#define D_   512
#define C_   8
#define P_   12
#define LOUT 244
#define O_   512
#define GM   3904   // 16*244 flattened M rows per channel

typedef __attribute__((ext_vector_type(8))) short bf16x8;
typedef __attribute__((ext_vector_type(4))) float f32x4;

__device__ __forceinline__ unsigned short f2bf(float f) {
    unsigned int u = __float_as_uint(f);
    unsigned int r = (u + 0x7FFFu + ((u >> 16) & 1u)) >> 16;
    return (unsigned short)r;
}

__device__ __forceinline__ void async_copy16(const void* g, void* l) {
    __builtin_amdgcn_global_load_lds(
        (const __attribute__((address_space(1))) unsigned int*)g,
        (__attribute__((address_space(3))) unsigned int*)l, 16, 0, 0);
}

// ---------------------------------------------------------------------------
// prep: blocks [0,976)  : tmp[c][b][l][d] = sum_p Wt[c,p]*inp[b,l+p,d] (bf16)
//                         one inp read serves all 8 channels (Wt via LDS)
//       blocks [976,3024): Ws f32 -> bf16 (one float4/thread)
// ---------------------------------------------------------------------------
__global__ __launch_bounds__(256) void prep(const float* __restrict__ inp,
                                            const float* __restrict__ Ws,
                                            const float* __restrict__ Wt,
                                            unsigned short* __restrict__ tmp,
                                            unsigned short* __restrict__ wsb) {
    int bid = blockIdx.x;
    int tid = threadIdx.x;

    if (bid >= 976) {                       // ---- Ws convert path ----
        int g = (bid - 976) * 256 + tid;    // 524288 float4s
        float4 v = ((const float4*)Ws)[g];
        ushort4 o;
        o.x = f2bf(v.x); o.y = f2bf(v.y); o.z = f2bf(v.z); o.w = f2bf(v.w);
        ((ushort4*)wsb)[g] = o;
        return;
    }

    // ---- FIR path ----
    __shared__ float wt_s[C_][P_];
    if (tid < C_ * P_) wt_s[tid / P_][tid % P_] = Wt[tid];
    __syncthreads();

    int b = bid / 61, lg = bid % 61;
    int l0 = lg * 4;
    int d0 = tid * 2;

    float2 rows[15];
    const float* ibase = inp + ((size_t)b * L_ + l0) * D_ + d0;
#pragma unroll
    for (int j = 0; j < 15; ++j)
        rows[j] = *(const float2*)(ibase + (size_t)j * D_);

#pragma unroll
    for (int c = 0; c < C_; ++c) {
        float w[P_];
#pragma unroll
        for (int p = 0; p < P_; ++p) w[p] = wt_s[c][p];
        unsigned short* ob = tmp + (((size_t)(c * B_ + b)) * LOUT + l0) * D_ + d0;
#pragma unroll
        for (int j = 0; j < 4; ++j) {
            float vx = 0.f, vy = 0.f;
#pragma unroll
            for (int p = 0; p < P_; ++p) {
                vx += w[p] * rows[j + p].x;
                vy += w[p] * rows[j + p].y;
            }
            ushort2 ov; ov.x = f2bf(vx); ov.y = f2bf(vy);
            *(ushort2*)(ob + (size_t)j * D_) = ov;
        }
    }
}

// ---------------------------------------------------------------------------
// gemm: per c: out[r,o] = tmp[r,:] . Ws[c,o,:] + S*bs[c,o] + bt[c]
// m97 structure: 128x128 tile, BK=64, global_load_lds x16, 4 waves (2x2),
// 4x4 frags of v_mfma_f32_16x16x32_bf16, 2-barrier K-loop.
// bid mapping packs the 4 ot-siblings of a (c,mt) group at bids = same mod 8
// so they share one XCD's L2 (tmp rows fetched from HBM once).
// ---------------------------------------------------------------------------
__global__ __launch_bounds__(256) void gemm_k(const unsigned short* __restrict__ tmp,
                                              const unsigned short* __restrict__ wsb,
                                              const float* __restrict__ bs,
                                              const float* __restrict__ Wt,
                                              const float* __restrict__ bt,
                                              float* __restrict__ out) {
    __shared__ unsigned short As[128 * 64];
    __shared__ unsigned short Bs[128 * 64];

    // bid = (g%8) + 8*(ot + 4*(g/8)),  g = c*31 + mt   (992 blocks total)
    int bid = blockIdx.x;
    int gr = bid & 7;
    int t  = bid >> 3;
    int ot = t & 3;
    int gq = t >> 2;
    int g  = gq * 8 + gr;
    int c  = g / 31;
    int mt = g % 31;

    int row0 = mt * 128, o0 = ot * 128;
    int tid = threadIdx.x, lane = tid & 63, wid = tid >> 6;
    int wm = wid >> 1, wn = wid & 1;

    const unsigned short* Ab = tmp + (size_t)c * GM * D_;
    const unsigned short* Bb = wsb + (size_t)c * O_ * D_;

    f32x4 acc[4][4];
#pragma unroll
    for (int m = 0; m < 4; ++m)
#pragma unroll
        for (int n = 0; n < 4; ++n)
            acc[m][n] = (f32x4){0.f, 0.f, 0.f, 0.f};

    for (int d0 = 0; d0 < D_; d0 += 64) {
        __syncthreads();
#pragma unroll
        for (int h = 0; h < 4; ++h) {
            int q = h * 256 + tid;           // 1024 16B-chunks per tile
            int row = q >> 3, col = (q & 7) * 8;
            int ar = row0 + row; if (ar > GM - 1) ar = GM - 1;
            async_copy16(Ab + (size_t)ar * D_ + d0 + col,
                         (unsigned short*)As + (size_t)q * 8);
            async_copy16(Bb + (size_t)(o0 + row) * D_ + d0 + col,
                         (unsigned short*)Bs + (size_t)q * 8);
        }
        __syncthreads();   // compiler drains vmcnt(0) here (m97 pattern)

#pragma unroll
        for (int kk = 0; kk < 2; ++kk) {
            int cb = kk * 32 + ((lane >> 4) << 3);
            bf16x8 af[4], bq[4];
#pragma unroll
            for (int m = 0; m < 4; ++m)
                af[m] = *(const bf16x8*)&As[(wm * 64 + m * 16 + (lane & 15)) * 64 + cb];
#pragma unroll
            for (int n = 0; n < 4; ++n)
                bq[n] = *(const bf16x8*)&Bs[(wn * 64 + n * 16 + (lane & 15)) * 64 + cb];
#pragma unroll
            for (int m = 0; m < 4; ++m)
#pragma unroll
                for (int n = 0; n < 4; ++n)
                    acc[m][n] = __builtin_amdgcn_mfma_f32_16x16x32_bf16(
                        af[m], bq[n], acc[m][n], 0, 0, 0);
        }
    }

    float S = 0.f;
#pragma unroll
    for (int p = 0; p < P_; ++p) S += Wt[c * P_ + p];
    float btc = bt[c];

#pragma unroll
    for (int m = 0; m < 4; ++m) {
        int rb = row0 + wm * 64 + m * 16 + ((lane >> 4) << 2);
#pragma unroll
        for (int n = 0; n < 4; ++n) {
            int col = o0 + wn * 64 + n * 16 + (lane & 15);
            float add = bs[c * O_ + col] * S + btc;
#pragma unroll
            for (int i = 0; i < 4; ++i) {
                int r = rb + i;
                if (r < GM)
                    out[((size_t)r * C_ + c) * O_ + col] = acc[m][n][i] + add;
            }
        }
    }
}

// ---------------------------------------------------------------------------
// Fallback (ws too small): slow but correct, no workspace.
// ---------------------------------------------------------------------------
__global__ __launch_bounds__(256) void naive_k(const float* __restrict__ inp,
                                               const float* __restrict__ Ws,
                                               const float* __restrict__ bs,
                                               const float* __restrict__ Wt,
                                               const float* __restrict__ bt,
                                               float* __restrict__ out) {
    __shared__ float tmp[D_];
    int bid = blockIdx.x;
    int c = bid & 7; int r = bid >> 3;
    int l = r % LOUT; int b = r / LOUT;
    int tid = threadIdx.x;

    for (int d = tid; d < D_; d += 256) {
        float s = 0.f;
        for (int p = 0; p < P_; ++p)
            s += Wt[c * P_ + p] * inp[((size_t)b * L_ + l + p) * D_ + d];
        tmp[d] = s;
    }
    __syncthreads();
    float S = 0.f;
    for (int p = 0; p < P_; ++p) S += Wt[c * P_ + p];
    for (int o = tid; o < O_; o += 256) {
        const float* wrow = Ws + ((size_t)c * O_ + o) * D_;
        float s = 0.f;
        for (int d = 0; d < D_; ++d) s += wrow[d] * tmp[d];
        out[(((size_t)b * LOUT + l) * C_ + c) * O_ + o] =
            s + bs[c * O_ + o] * S + bt[c];
    }
}

extern "C" void kernel_launch(void* const* d_in, const int* in_sizes, int n_in,
                              void* d_out, int out_size, void* d_ws, size_t ws_size,
                              hipStream_t stream) {
    const float* inp = (const float*)d_in[0];
    const float* Ws  = (const float*)d_in[1];
    const float* bs  = (const float*)d_in[2];
    const float* Wt  = (const float*)d_in[3];
    const float* bt  = (const float*)d_in[4];
    float* out = (float*)d_out;

    const size_t TMPB = (size_t)C_ * GM * D_ * 2;          // 31,981,568
    const size_t WSBB = (size_t)C_ * O_ * D_ * 2;          //  4,194,304

    if (ws_size >= TMPB + WSBB) {
        unsigned short* tmpb = (unsigned short*)d_ws;
        unsigned short* wsb  = (unsigned short*)((char*)d_ws + TMPB);
        prep<<<3024, 256, 0, stream>>>(inp, Ws, Wt, tmpb, wsb);
        gemm_k<<<992, 256, 0, stream>>>(tmpb, wsb, bs, Wt, bt, out);
    } else {
        naive_k<<<B_ * LOUT * C_, 256, 0, stream>>>(inp, Ws, bs, Wt, bt, out);
    }
}